// Round 1
// 1190.021 us; speedup vs baseline: 1.2514x; 1.2514x over previous
//
#include <hip/hip_runtime.h>
#include <stdint.h>

typedef unsigned short u16;
typedef __attribute__((ext_vector_type(8))) short bfrag;   // 8 bf16 = 4 VGPR MFMA operand
typedef __attribute__((ext_vector_type(4))) float f32x4;   // MFMA accumulator

#define DEVI __device__ __forceinline__

DEVI float b2f(u16 u){ return __uint_as_float(((uint32_t)u) << 16); }
DEVI u16 f2b(float f){
  uint32_t x = __float_as_uint(f);
  uint32_t r = (x + 0x7fffu + ((x >> 16) & 1u)) >> 16;   // RNE
  return (u16)r;
}
DEVI float silu_f(float v){ return v / (1.0f + __expf(-v)); }

// ---- transposed-weight arena element offsets (bf16 elements) ----
#define OFF_KJ   0
#define OFF_DOWN 16384
#define OFF_JI   24576
#define OFF_UP   122880
#define OFF_BS1  172032
#define OFF_BS2  270336
#define OFF_LIN  368640
#define OFF_AS1  466944
#define OFF_AS2  565248
#define WT_TOTAL 663552

struct TW {
  const float *kj, *down, *ji, *up, *bs1, *bs2, *lin, *as1, *as2;
  u16* dst;
};

// Transpose+convert all weight matrices fp32 [K,N] -> bf16 [N,K] once.
__global__ void __launch_bounds__(256) k_transpose(TW p){
  int id = blockIdx.y;
  const float* src; int K, N; int doff;
  if      (id == 0) { src = p.kj;                K = 128; N = 128; doff = OFF_KJ; }
  else if (id == 1) { src = p.down;              K = 128; N = 64;  doff = OFF_DOWN; }
  else if (id < 8)  { int b = id - 2;  src = p.ji  + b*16384; K = 128; N = 128; doff = OFF_JI  + b*16384; }
  else if (id < 14) { int b = id - 8;  src = p.up  + b*8192;  K = 64;  N = 128; doff = OFF_UP  + b*8192;  }
  else if (id < 20) { int b = id - 14; src = p.bs1 + b*16384; K = 128; N = 128; doff = OFF_BS1 + b*16384; }
  else if (id < 26) { int b = id - 20; src = p.bs2 + b*16384; K = 128; N = 128; doff = OFF_BS2 + b*16384; }
  else if (id < 32) { int b = id - 26; src = p.lin + b*16384; K = 128; N = 128; doff = OFF_LIN + b*16384; }
  else if (id < 38) { int b = id - 32; src = p.as1 + b*16384; K = 128; N = 128; doff = OFF_AS1 + b*16384; }
  else              { int b = id - 38; src = p.as2 + b*16384; K = 128; N = 128; doff = OFF_AS2 + b*16384; }
  int idx = blockIdx.x*256 + threadIdx.x;
  if (idx >= K*N) return;
  int n = idx / K, k = idx - n*K;
  p.dst[doff + idx] = f2b(src[k*N + n]);
}

// elementwise fp32 -> bf16
__global__ void __launch_bounds__(256) k_f2b(
    const float* __restrict__ src, u16* __restrict__ dst, int n)
{
  int i = blockIdx.x*256 + threadIdx.x;
  if (i < n) dst[i] = f2b(src[i]);
}

// rbf2[e,h] = ((rbf @ W_rbf1) @ W_rbf2)[e,h]  (fp32 in, bf16 out)
__global__ void __launch_bounds__(256) k_rbf(
    const float* __restrict__ rbf, const float* __restrict__ W1,
    const float* __restrict__ W2, u16* __restrict__ out, int E)
{
  __shared__ float w1s[48];
  __shared__ float w2s[1024];
  for (int i = threadIdx.x; i < 48;   i += 256) w1s[i] = W1[i];
  for (int i = threadIdx.x; i < 1024; i += 256) w2s[i] = W2[i];
  __syncthreads();
  int idx = blockIdx.x*256 + threadIdx.x;
  if (idx >= E*128) return;
  int e = idx >> 7, h = idx & 127;
  float rv[6];
#pragma unroll
  for (int k = 0; k < 6; k++) rv[k] = rbf[e*6 + k];
  float o = 0.f;
#pragma unroll
  for (int j = 0; j < 8; j++){
    float m = 0.f;
#pragma unroll
    for (int k = 0; k < 6; k++) m += rv[k] * w1s[k*8 + j];
    o += m * w2s[j*128 + h];
  }
  out[idx] = f2b(o);
}

// s1[t,0:8] = (sbf @ W_sbf1)[t]  (fp32 in, fp32 out)
__global__ void __launch_bounds__(256) k_s1(
    const float* __restrict__ sbf, const float* __restrict__ W1,
    float* __restrict__ s1, int T)
{
  __shared__ float w1s[336];
  for (int i = threadIdx.x; i < 336; i += 256) w1s[i] = W1[i];
  __syncthreads();
  int t = blockIdx.x*256 + threadIdx.x;
  if (t >= T) return;
  const float* row = sbf + (size_t)t*42;
  float a[8];
#pragma unroll
  for (int j = 0; j < 8; j++) a[j] = 0.f;
  for (int k = 0; k < 42; k++){
    float sv = row[k];
#pragma unroll
    for (int j = 0; j < 8; j++) a[j] += sv * w1s[k*8 + j];
  }
#pragma unroll
  for (int j = 0; j < 8; j++) s1[(size_t)t*8 + j] = a[j];
}

// one wave per triplet: sbf_e = s1 @ W_sbf2; v = x_kj[idx_kj]*sbf_e; scatter into agg[branch]
__global__ void __launch_bounds__(256) k_triplet(
    const int* __restrict__ idx_kj, const int* __restrict__ idx_ji,
    const int* __restrict__ bt, const float* __restrict__ s1,
    const float* __restrict__ Wsbf2, const u16* __restrict__ xkj,
    float* __restrict__ agg, int T, int E)
{
  int g = blockIdx.x*256 + threadIdx.x;
  int t = g >> 6, lane = g & 63;
  if (t >= T) return;
  int kj = idx_kj[t], ji = idx_ji[t];
  int b = bt[kj] + 1;
  b = b < 0 ? 0 : (b > 5 ? 5 : b);
  float se = 0.f;
#pragma unroll
  for (int j = 0; j < 8; j++) se += s1[(size_t)t*8 + j] * Wsbf2[j*64 + lane];
  float v = b2f(xkj[(size_t)kj*64 + lane]) * se;
  unsafeAtomicAdd(&agg[((size_t)b*E + ji)*64 + lane], v);
}

// agg fp32 -> aggb bf16 slots 0..5, slot 6 = sum (== agg_gen)
__global__ void __launch_bounds__(256) k_cvt(
    const float* __restrict__ agg, u16* __restrict__ aggb, int EI)
{
  int idx = blockIdx.x*256 + threadIdx.x;
  if (idx >= EI) return;
  float s = 0.f;
#pragma unroll
  for (int b = 0; b < 6; b++){
    float v = agg[(size_t)b*EI + idx];
    s += v;
    aggb[(size_t)b*EI + idx] = f2b(v);
  }
  aggb[(size_t)6*EI + idx] = f2b(s);
}

// reduce nsl slices of S into out (fp32): scale = (genLast && last) ? alpha : (1-alpha)
__global__ void __launch_bounds__(256) k_red(
    const u16* __restrict__ S, const float* __restrict__ alphaP,
    float* __restrict__ out, size_t EH, int nsl, int genLast, int accum)
{
  size_t base = ((size_t)blockIdx.x*256 + threadIdx.x)*4;
  if (base >= EH) return;
  float al = alphaP[0];
  float s0=0,s1=0,s2=0,s3=0;
  for (int c = 0; c < nsl; c++){
    float sc = (genLast && c == nsl-1) ? al : (1.f - al);
    ushort4 v = *(const ushort4*)&S[(size_t)c*EH + base];
    s0 += sc*b2f(v.x); s1 += sc*b2f(v.y); s2 += sc*b2f(v.z); s3 += sc*b2f(v.w);
  }
  float4 o;
  if (accum){
    float4 p = *(const float4*)&out[base];
    o.x = p.x + s0; o.y = p.y + s1; o.z = p.z + s2; o.w = p.w + s3;
  } else {
    o.x = s0; o.y = s1; o.z = s2; o.w = s3;
  }
  *(float4*)&out[base] = o;
}

// ================== batched fused-epilogue MFMA GEMM (pre-chain) ==================
// grid (mt, nsl). Slice sl=blockIdx.y: A+sl*aStr [M,K] @ W[min(cBase+sl,5)] [K,N]
// -> out+sl*oStr.  MODE 0: out = silu(AW+b)*aux;  MODE 1: out = silu(AW+b)(+aux).
template<int MODE, int N, int K>
__global__ void __launch_bounds__(256) k_gemmb(
    const u16* __restrict__ A, size_t aStr,
    const u16* __restrict__ WTp, int wStr,
    const float* __restrict__ bias, int bStr,
    const u16* __restrict__ aux, size_t xStr,
    u16* __restrict__ out, size_t oStr,
    int cBase, int M)
{
  constexpr int KP = K + 8;                  // bf16 pad: 2-way aliasing (free)
  constexpr int PITCH = N + 4;               // f32 epilogue pitch
  constexpr size_t SW = (size_t)KP*N*2;
  constexpr size_t SE = (size_t)64*PITCH*4;  // 64 rows per epilogue pass
  constexpr size_t SMEM = SW > SE ? SW : SE;
  __shared__ __attribute__((aligned(16))) char smem[SMEM];
  u16*   wlds = (u16*)smem;
  float* elds = (float*)smem;

  const int tid = threadIdx.x;
  const int sl = blockIdx.y;
  const int c = cBase + sl;
  const int wsel = c < 5 ? c : 5;
  const u16* __restrict__ Ac = A + (size_t)sl*aStr;
  const u16* __restrict__ Wc = WTp + (size_t)wsel*wStr;
  const u16* __restrict__ auxc = aux ? aux + (size_t)sl*xStr : (const u16*)0;
  u16* __restrict__ outc = out + (size_t)sl*oStr;

  // stage weights [N,K] bf16 -> LDS
  constexpr int CH = (N*K)/8;
  for (int ch = tid; ch < CH; ch += 256){
    int n  = ch / (K/8);
    int kc = (ch - n*(K/8))*8;
    *(int4*)&wlds[n*KP + kc] = *(const int4*)&Wc[n*K + kc];
  }
  __syncthreads();

  const int wave = tid >> 6, lane = tid & 63;
  const int lr = lane & 15, lq = lane >> 4;
  const int m0 = blockIdx.x*128 + wave*32;
  constexpr int NBN = N/16;
  f32x4 acc[2][NBN];
#pragma unroll
  for (int i = 0; i < 2; i++)
#pragma unroll
    for (int j = 0; j < NBN; j++) acc[i][j] = (f32x4){0.f,0.f,0.f,0.f};

  const int r0 = m0 + lr;
#pragma unroll
  for (int ks = 0; ks < K/32; ks++){
    const int k0 = ks*32 + lq*8;
    bfrag a0 = {0,0,0,0,0,0,0,0}, a1 = {0,0,0,0,0,0,0,0};
    if (r0 < M)      a0 = *(const bfrag*)&Ac[(size_t)r0*K + k0];
    if (r0 + 16 < M) a1 = *(const bfrag*)&Ac[(size_t)(r0+16)*K + k0];
#pragma unroll
    for (int nb = 0; nb < NBN; nb++){
      bfrag bv = *(const bfrag*)&wlds[(nb*16 + lr)*KP + k0];
      acc[0][nb] = __builtin_amdgcn_mfma_f32_16x16x32_bf16(a0, bv, acc[0][nb], 0, 0, 0);
      acc[1][nb] = __builtin_amdgcn_mfma_f32_16x16x32_bf16(a1, bv, acc[1][nb], 0, 0, 0);
    }
  }

  float bv[NBN];
#pragma unroll
  for (int nb = 0; nb < NBN; nb++)
    bv[nb] = bias ? bias[wsel*bStr + nb*16 + lr] : 0.f;

#pragma unroll
  for (int mb = 0; mb < 2; mb++){
    __syncthreads();
#pragma unroll
    for (int nb = 0; nb < NBN; nb++){
      const int col = nb*16 + lr;
#pragma unroll
      for (int r = 0; r < 4; r++){
        float v = silu_f(acc[mb][nb][r] + bv[nb]);
        elds[(wave*16 + lq*4 + r)*PITCH + col] = v;
      }
    }
    __syncthreads();
    constexpr int CHUNKS = 64*N/4;
    for (int q = tid; q < CHUNKS; q += 256){
      int lrow = q / (N/4);
      int col0 = (q - lrow*(N/4))*4;
      int w = lrow >> 4, rr = lrow & 15;
      int grow = blockIdx.x*128 + w*32 + mb*16 + rr;
      if (grow >= M) continue;
      float4 v = *(float4*)&elds[lrow*PITCH + col0];
      size_t oi = (size_t)grow*N + col0;
      float o0 = v.x, o1 = v.y, o2 = v.z, o3 = v.w;
      if (MODE == 0){
        ushort4 av = *(const ushort4*)&auxc[oi];
        o0 *= b2f(av.x); o1 *= b2f(av.y); o2 *= b2f(av.z); o3 *= b2f(av.w);
      } else if (auxc){
        ushort4 av = *(const ushort4*)&auxc[oi];
        o0 += b2f(av.x); o1 += b2f(av.y); o2 += b2f(av.z); o3 += b2f(av.w);
      }
      ushort4 ov; ov.x = f2b(o0); ov.y = f2b(o1); ov.z = f2b(o2); ov.w = f2b(o3);
      *(ushort4*)&outc[oi] = ov;
    }
  }
}

// ================== fully-fused per-slice chain ==================
// grid (ceil(E/256), 7), 512 threads = 8 waves x 32-row strips.
// Per block: 7 back-to-back GEMMs (UP,JI,BS1,BS2,LIN,AS1,AS2) over a 256-row
// tile. N=128 = full width so the tile is closed under the chain.
// Intermediates live in a per-wave-PRIVATE LDS tile (bf16, pitch 136) +
// packed-bf16 registers (t1/h/h2) -- the lane<->(row,col) ownership map is
// bijective, so no barriers are needed for the tile round trips.
// Weights pipeline through ONE LDS buffer: reg-staged global->reg at stage
// start (latency hidden under 64 MFMAs), ds_write between two barriers.
__global__ void __launch_bounds__(512) k_chain(
    const u16* __restrict__ XB, const u16* __restrict__ AGGB,
    const u16* __restrict__ WTb,
    const float* __restrict__ bji, const float* __restrict__ bbs1,
    const float* __restrict__ bbs2, const float* __restrict__ blin,
    const float* __restrict__ bas1, const float* __restrict__ bas2,
    u16* __restrict__ OUT, int E)
{
  constexpr int KP = 136;    // K=128 pitch: bank stride 4*lr mod 32 -> 2-way, free
  constexpr int KP64 = 72;   // K=64 pitch: same property
  __shared__ __attribute__((aligned(16))) u16 wlds[128*KP];     // 34,816 B
  __shared__ __attribute__((aligned(16))) u16 tlds[8*32*KP];    // 69,632 B

  const int tid = threadIdx.x;
  const int wave = tid >> 6, lane = tid & 63;
  const int lr = lane & 15, lq = lane >> 4;
  const int sl = blockIdx.y;
  const int b  = sl < 5 ? sl : 5;
  const size_t EH = (size_t)E*128, EI = (size_t)E*64;
  const int m0 = blockIdx.x*256 + wave*32;
  u16* tw = tlds + wave*(32*KP);

  const u16* Wji  = WTb + OFF_JI  + b*16384;
  const u16* Wbs1 = WTb + OFF_BS1 + b*16384;
  const u16* Wbs2 = WTb + OFF_BS2 + b*16384;
  const u16* Wlin = WTb + OFF_LIN + b*16384;
  const u16* Was1 = WTb + OFF_AS1 + b*16384;
  const u16* Was2 = WTb + OFF_AS2 + b*16384;

  f32x4 acc[2][8];
  uint32_t t1p[2][8][2], hp[2][8][2], h2p[2][8][2];
  int4 wr0, wr1, wr2, wr3;
  float bv8[8];

  auto zacc = [&]{
#pragma unroll
    for (int i = 0; i < 2; i++)
#pragma unroll
      for (int j = 0; j < 8; j++) acc[i][j] = (f32x4){0.f,0.f,0.f,0.f};
  };
  auto issueW = [&](const u16* W){            // 4 x dwordx4 per thread = 32 KB/block
    wr0 = *(const int4*)&W[(size_t)tid*8];
    wr1 = *(const int4*)&W[(size_t)(tid+512)*8];
    wr2 = *(const int4*)&W[(size_t)(tid+1024)*8];
    wr3 = *(const int4*)&W[(size_t)(tid+1536)*8];
  };
  auto writeW = [&]{                          // dense [N,K] chunks -> [N][KP] LDS
    const int c0 = tid, c1 = tid+512, c2 = tid+1024, c3 = tid+1536;
    *(int4*)&wlds[(c0>>4)*KP + (c0&15)*8] = wr0;
    *(int4*)&wlds[(c1>>4)*KP + (c1&15)*8] = wr1;
    *(int4*)&wlds[(c2>>4)*KP + (c2&15)*8] = wr2;
    *(int4*)&wlds[(c3>>4)*KP + (c3&15)*8] = wr3;
  };
  auto mfmaT = [&]{                           // A from private tile, K=128
    zacc();
#pragma unroll
    for (int ks = 0; ks < 4; ks++){
      const int k0 = ks*32 + lq*8;
      bfrag a0 = *(const bfrag*)&tw[lr*KP + k0];
      bfrag a1 = *(const bfrag*)&tw[(lr+16)*KP + k0];
#pragma unroll
      for (int nb = 0; nb < 8; nb++){
        bfrag bvv = *(const bfrag*)&wlds[(nb*16+lr)*KP + k0];
        acc[0][nb] = __builtin_amdgcn_mfma_f32_16x16x32_bf16(a0, bvv, acc[0][nb], 0,0,0);
        acc[1][nb] = __builtin_amdgcn_mfma_f32_16x16x32_bf16(a1, bvv, acc[1][nb], 0,0,0);
      }
    }
  };
  auto biasv = [&](const float* bp){
#pragma unroll
    for (int nb = 0; nb < 8; nb++) bv8[nb] = bp[b*128 + nb*16 + lr];
  };
  auto pk = [](float lo, float hi){ return (uint32_t)f2b(lo) | ((uint32_t)f2b(hi) << 16); };
  auto tstore = [&](int mb, int nb, float v0, float v1, float v2, float v3){
    const int base = (mb*16 + lq*4)*KP + nb*16 + lr;
    tw[base]        = f2b(v0);
    tw[base +   KP] = f2b(v1);
    tw[base + 2*KP] = f2b(v2);
    tw[base + 3*KP] = f2b(v3);
  };

  // ---- prologue: W_up -> wlds (pitch KP64) ----
  {
    const u16* Wup = WTb + OFF_UP + b*8192;
    int4 w0 = *(const int4*)&Wup[(size_t)tid*8];
    int4 w1 = *(const int4*)&Wup[(size_t)(tid+512)*8];
    const int c0 = tid, c1 = tid+512;
    *(int4*)&wlds[(c0>>3)*KP64 + (c0&7)*8] = w0;
    *(int4*)&wlds[(c1>>3)*KP64 + (c1&7)*8] = w1;
  }
  __syncthreads();

  // ---- s1: t1 = silu(agg_sl @ W_up)  [K=64] ----
  issueW(Wji);
  {
    zacc();
    const u16* Ag = AGGB + (size_t)sl*EI;
    const int r0 = m0 + lr;
#pragma unroll
    for (int ks = 0; ks < 2; ks++){
      const int k0 = ks*32 + lq*8;
      bfrag a0 = (bfrag){0,0,0,0,0,0,0,0}, a1 = (bfrag){0,0,0,0,0,0,0,0};
      if (r0 < E)      a0 = *(const bfrag*)&Ag[(size_t)r0*64 + k0];
      if (r0 + 16 < E) a1 = *(const bfrag*)&Ag[(size_t)(r0+16)*64 + k0];
#pragma unroll
      for (int nb = 0; nb < 8; nb++){
        bfrag bvv = *(const bfrag*)&wlds[(nb*16+lr)*KP64 + k0];
        acc[0][nb] = __builtin_amdgcn_mfma_f32_16x16x32_bf16(a0, bvv, acc[0][nb], 0,0,0);
        acc[1][nb] = __builtin_amdgcn_mfma_f32_16x16x32_bf16(a1, bvv, acc[1][nb], 0,0,0);
      }
    }
#pragma unroll
    for (int mb = 0; mb < 2; mb++)
#pragma unroll
      for (int nb = 0; nb < 8; nb++){
        t1p[mb][nb][0] = pk(silu_f(acc[mb][nb][0]), silu_f(acc[mb][nb][1]));
        t1p[mb][nb][1] = pk(silu_f(acc[mb][nb][2]), silu_f(acc[mb][nb][3]));
      }
  }
  __syncthreads();
  writeW();            // wlds = W_ji
  __syncthreads();

  // ---- s2: h = silu(x @ W_ji + bji) + t1 ----
  issueW(Wbs1);
  biasv(bji);
  {
    zacc();
    const int r0 = m0 + lr;
#pragma unroll
    for (int ks = 0; ks < 4; ks++){
      const int k0 = ks*32 + lq*8;
      bfrag a0 = (bfrag){0,0,0,0,0,0,0,0}, a1 = (bfrag){0,0,0,0,0,0,0,0};
      if (r0 < E)      a0 = *(const bfrag*)&XB[(size_t)r0*128 + k0];
      if (r0 + 16 < E) a1 = *(const bfrag*)&XB[(size_t)(r0+16)*128 + k0];
#pragma unroll
      for (int nb = 0; nb < 8; nb++){
        bfrag bvv = *(const bfrag*)&wlds[(nb*16+lr)*KP + k0];
        acc[0][nb] = __builtin_amdgcn_mfma_f32_16x16x32_bf16(a0, bvv, acc[0][nb], 0,0,0);
        acc[1][nb] = __builtin_amdgcn_mfma_f32_16x16x32_bf16(a1, bvv, acc[1][nb], 0,0,0);
      }
    }
#pragma unroll
    for (int mb = 0; mb < 2; mb++)
#pragma unroll
      for (int nb = 0; nb < 8; nb++){
        float v0 = silu_f(acc[mb][nb][0] + bv8[nb]) + b2f((u16)(t1p[mb][nb][0] & 0xffffu));
        float v1 = silu_f(acc[mb][nb][1] + bv8[nb]) + b2f((u16)(t1p[mb][nb][0] >> 16));
        float v2 = silu_f(acc[mb][nb][2] + bv8[nb]) + b2f((u16)(t1p[mb][nb][1] & 0xffffu));
        float v3 = silu_f(acc[mb][nb][3] + bv8[nb]) + b2f((u16)(t1p[mb][nb][1] >> 16));
        hp[mb][nb][0] = pk(v0, v1);
        hp[mb][nb][1] = pk(v2, v3);
        tstore(mb, nb, v0, v1, v2, v3);
      }
  }
  __syncthreads();
  writeW();            // wlds = W_bs1
  __syncthreads();

  // ---- s3: t = silu(h @ W_bs1 + bbs1) ----
  issueW(Wbs2);
  biasv(bbs1);
  mfmaT();
#pragma unroll
  for (int mb = 0; mb < 2; mb++)
#pragma unroll
    for (int nb = 0; nb < 8; nb++)
      tstore(mb, nb, silu_f(acc[mb][nb][0]+bv8[nb]), silu_f(acc[mb][nb][1]+bv8[nb]),
                     silu_f(acc[mb][nb][2]+bv8[nb]), silu_f(acc[mb][nb][3]+bv8[nb]));
  __syncthreads();
  writeW();            // wlds = W_bs2
  __syncthreads();

  // ---- s4: h = h + silu(t @ W_bs2 + bbs2) ----
  issueW(Wlin);
  biasv(bbs2);
  mfmaT();
#pragma unroll
  for (int mb = 0; mb < 2; mb++)
#pragma unroll
    for (int nb = 0; nb < 8; nb++){
      float v0 = b2f((u16)(hp[mb][nb][0] & 0xffffu)) + silu_f(acc[mb][nb][0]+bv8[nb]);
      float v1 = b2f((u16)(hp[mb][nb][0] >> 16))     + silu_f(acc[mb][nb][1]+bv8[nb]);
      float v2 = b2f((u16)(hp[mb][nb][1] & 0xffffu)) + silu_f(acc[mb][nb][2]+bv8[nb]);
      float v3 = b2f((u16)(hp[mb][nb][1] >> 16))     + silu_f(acc[mb][nb][3]+bv8[nb]);
      hp[mb][nb][0] = pk(v0, v1); hp[mb][nb][1] = pk(v2, v3);
      tstore(mb, nb, v0, v1, v2, v3);
    }
  __syncthreads();
  writeW();            // wlds = W_lin
  __syncthreads();

  // ---- s5: h2 = silu(h @ W_lin + blin) + x ----
  issueW(Was1);
  biasv(blin);
  mfmaT();
  // coalesced x strip into tw (A-frag reads already issued; same-wave DS is in-order)
#pragma unroll
  for (int j = 0; j < 8; j++){
    const int c = lane + j*64;
    const int row = c >> 4, kc = (c & 15)*8;
    const int grow = m0 + row;
    int4 xv = (int4){0,0,0,0};
    if (grow < E) xv = *(const int4*)&XB[(size_t)grow*128 + kc];
    *(int4*)&tw[row*KP + kc] = xv;
  }
#pragma unroll
  for (int mb = 0; mb < 2; mb++)
#pragma unroll
    for (int nb = 0; nb < 8; nb++){
      const int base = (mb*16 + lq*4)*KP + nb*16 + lr;
      float v0 = silu_f(acc[mb][nb][0]+bv8[nb]) + b2f(tw[base]);
      float v1 = silu_f(acc[mb][nb][1]+bv8[nb]) + b2f(tw[base + KP]);
      float v2 = silu_f(acc[mb][nb][2]+bv8[nb]) + b2f(tw[base + 2*KP]);
      float v3 = silu_f(acc[mb][nb][3]+bv8[nb]) + b2f(tw[base + 3*KP]);
      h2p[mb][nb][0] = pk(v0, v1); h2p[mb][nb][1] = pk(v2, v3);
      tstore(mb, nb, v0, v1, v2, v3);   // each (row,col) owned by exactly one lane
    }
  __syncthreads();
  writeW();            // wlds = W_as1
  __syncthreads();

  // ---- s6: t2 = silu(h2 @ W_as1 + bas1) ----
  issueW(Was2);
  biasv(bas1);
  mfmaT();
#pragma unroll
  for (int mb = 0; mb < 2; mb++)
#pragma unroll
    for (int nb = 0; nb < 8; nb++)
      tstore(mb, nb, silu_f(acc[mb][nb][0]+bv8[nb]), silu_f(acc[mb][nb][1]+bv8[nb]),
                     silu_f(acc[mb][nb][2]+bv8[nb]), silu_f(acc[mb][nb][3]+bv8[nb]));
  __syncthreads();
  writeW();            // wlds = W_as2
  __syncthreads();

  // ---- s7: out = h2 + silu(t2 @ W_as2 + bas2) ----
  biasv(bas2);
  mfmaT();
#pragma unroll
  for (int mb = 0; mb < 2; mb++)
#pragma unroll
    for (int nb = 0; nb < 8; nb++){
      float v0 = b2f((u16)(h2p[mb][nb][0] & 0xffffu)) + silu_f(acc[mb][nb][0]+bv8[nb]);
      float v1 = b2f((u16)(h2p[mb][nb][0] >> 16))     + silu_f(acc[mb][nb][1]+bv8[nb]);
      float v2 = b2f((u16)(h2p[mb][nb][1] & 0xffffu)) + silu_f(acc[mb][nb][2]+bv8[nb]);
      float v3 = b2f((u16)(h2p[mb][nb][1] >> 16))     + silu_f(acc[mb][nb][3]+bv8[nb]);
      tstore(mb, nb, v0, v1, v2, v3);
    }
  // vectorized store of the strip
#pragma unroll
  for (int j = 0; j < 8; j++){
    const int c = lane + j*64;
    const int row = c >> 4, kc = (c & 15)*8;
    const int grow = m0 + row;
    if (grow < E)
      *(int4*)&OUT[(size_t)sl*EH + (size_t)grow*128 + kc] = *(const int4*)&tw[row*KP + kc];
  }
}

// ================== legacy (verified) serial GEMM ==================
enum { EPI_MUL = 0, EPI_ADD = 1, EPI_ACC = 2, EPI_FIN = 3 };

template<int MODE, int N, int K>
__global__ void __launch_bounds__(256) k_gemm(
    const u16* __restrict__ A, const u16* __restrict__ WT,
    const float* __restrict__ bias, const u16* __restrict__ aux,
    float* __restrict__ accF, u16* __restrict__ outB,
    float* __restrict__ outF, const float* __restrict__ alphaPtr, int M)
{
  constexpr int KP = K + 8;
  __shared__ __attribute__((aligned(16))) u16 lds[KP*N];
  const int tid = threadIdx.x;
  constexpr int CH = (N*K)/8;
  for (int ch = tid; ch < CH; ch += 256){
    int n  = ch / (K/8);
    int kc = (ch - n*(K/8))*8;
    *(int4*)&lds[n*KP + kc] = *(const int4*)&WT[n*K + kc];
  }
  __syncthreads();

  const int wave = tid >> 6, lane = tid & 63;
  const int lr = lane & 15, lq = lane >> 4;
  const int m0 = blockIdx.x*128 + wave*32;
  constexpr int NBN = N/16;
  f32x4 acc[2][NBN];
#pragma unroll
  for (int i = 0; i < 2; i++)
#pragma unroll
    for (int j = 0; j < NBN; j++) acc[i][j] = (f32x4){0.f,0.f,0.f,0.f};

  const int r0 = m0 + lr;
#pragma unroll
  for (int ks = 0; ks < K/32; ks++){
    const int k0 = ks*32 + lq*8;
    bfrag a0 = {0,0,0,0,0,0,0,0}, a1 = {0,0,0,0,0,0,0,0};
    if (r0 < M)      a0 = *(const bfrag*)&A[(size_t)r0*K + k0];
    if (r0 + 16 < M) a1 = *(const bfrag*)&A[(size_t)(r0+16)*K + k0];
#pragma unroll
    for (int nb = 0; nb < NBN; nb++){
      bfrag bv = *(const bfrag*)&lds[(nb*16 + lr)*KP + k0];
      acc[0][nb] = __builtin_amdgcn_mfma_f32_16x16x32_bf16(a0, bv, acc[0][nb], 0, 0, 0);
      acc[1][nb] = __builtin_amdgcn_mfma_f32_16x16x32_bf16(a1, bv, acc[1][nb], 0, 0, 0);
    }
  }

  float sc = 0.f;
  if (MODE == EPI_ACC || MODE == EPI_FIN){
    float al = alphaPtr[0];
    sc = (MODE == EPI_FIN) ? al : (1.0f - al);
  }

#pragma unroll
  for (int mb = 0; mb < 2; mb++){
    const int rowb = m0 + mb*16 + lq*4;
#pragma unroll
    for (int nb = 0; nb < NBN; nb++){
      const int col = nb*16 + lr;
      const float bvv = bias ? bias[col] : 0.f;
#pragma unroll
      for (int r = 0; r < 4; r++){
        const int row = rowb + r;
        if (row >= M) continue;
        const size_t oi = (size_t)row*N + col;
        float v = silu_f(acc[mb][nb][r] + bvv);
        if (MODE == EPI_MUL){
          v *= b2f(aux[oi]);
          outB[oi] = f2b(v);
        } else if (MODE == EPI_ADD){
          if (aux) v += b2f(aux[oi]);
          outB[oi] = f2b(v);
        } else if (MODE == EPI_ACC){
          v += b2f(aux[oi]);
          accF[oi] += sc*v;
        } else {
          v += b2f(aux[oi]);
          outF[oi] = sc*v + accF[oi];
        }
      }
    }
  }
}

extern "C" void kernel_launch(void* const* d_in, const int* in_sizes, int n_in,
                              void* d_out, int out_size, void* d_ws, size_t ws_size,
                              hipStream_t stream)
{
  const float* x     = (const float*)d_in[0];
  const float* rbf   = (const float*)d_in[1];
  const float* sbf   = (const float*)d_in[2];
  const int*   ikj   = (const int*)d_in[3];
  const int*   iji   = (const int*)d_in[4];
  const int*   bt    = (const int*)d_in[5];
  const float* alphaP= (const float*)d_in[6];
  const float* Wrbf1 = (const float*)d_in[8];
  const float* Wrbf2 = (const float*)d_in[9];
  const float* Wsbf1 = (const float*)d_in[10];
  const float* Wsbf2 = (const float*)d_in[11];
  const float* Wkj   = (const float*)d_in[12];
  const float* bkj   = (const float*)d_in[13];
  const float* Wji   = (const float*)d_in[14];
  const float* bji   = (const float*)d_in[15];
  const float* Wdown = (const float*)d_in[16];
  const float* Wup   = (const float*)d_in[17];
  const float* Wbs1  = (const float*)d_in[18];
  const float* bbs1  = (const float*)d_in[19];
  const float* Wbs2  = (const float*)d_in[20];
  const float* bbs2  = (const float*)d_in[21];
  const float* Wlin  = (const float*)d_in[22];
  const float* blin  = (const float*)d_in[23];
  const float* Was1  = (const float*)d_in[24];
  const float* bas1  = (const float*)d_in[25];
  const float* Was2  = (const float*)d_in[26];
  const float* bas2  = (const float*)d_in[27];

  const int E = in_sizes[5];
  const int T = in_sizes[3];
  const int H = 128, I = 64;
  const size_t EH = (size_t)E*H, EI = (size_t)E*I;
  const int mt = (E + 127)/128;

  TW tw{Wkj, Wdown, Wji, Wup, Wbs1, Wbs2, Wlin, Was1, Was2, (u16*)0};

  // ---------- batched arena (same proven 334.1 MB footprint) ----------
  {
    char* ws = (char*)d_ws;
    size_t off = 0;
    auto arena = [&](size_t bytes)->size_t{
      size_t o = off; off += (bytes + 255) & ~(size_t)255; return o;
    };
    size_t oWT   = arena((size_t)WT_TOTAL*2);   // 1.33 MB
    size_t oXB   = arena(EH*2);                 // 25.6 MB
    size_t oXKJ  = arena(EI*2);                 // 12.8 MB
    size_t oAGGB = arena(7*EI*2);               // 89.6 MB
    size_t oBUF  = arena(2*(4*EH*2));           // 204.8 MB
    // pre-chain aliases inside BUF:
    //   AGG  fp32 6*EI*4 = 153.6 MB at BUF+0       (dead after k_cvt)
    //   S1   fp32 T*8*4  = 19.2 MB  at BUF+153.6   (dead after k_triplet)
    //   RBF2 bf16 EH*2   at BUF+0                  (dead after KJ)
    //   TMP  bf16 EH*2   at BUF+172.8              (dead after DOWN)
    // chain: OUT bf16 7*EH*2 = 179.2 MB at BUF+0   (written after all above die)

    if (off <= ws_size){
      u16*   WTb  = (u16*)(ws + oWT);
      u16*   XB   = (u16*)(ws + oXB);
      u16*   XKJ  = (u16*)(ws + oXKJ);
      u16*   AGGB = (u16*)(ws + oAGGB);
      char*  BUF  = ws + oBUF;
      u16*   OUT  = (u16*)BUF;
      float* AGG  = (float*)BUF;
      float* S1   = (float*)(BUF + 6*EI*4);
      u16*   RBF2 = (u16*)BUF;
      u16*   TMP  = (u16*)(BUF + 6*EI*4 + (size_t)T*8*4);

      tw.dst = WTb;
      hipLaunchKernelGGL(k_transpose, dim3(64, 44, 1), dim3(256, 1, 1), 0, stream, tw);
      k_f2b<<<dim3((int)((EH + 255)/256)), dim3(256), 0, stream>>>(x, XB, (int)EH);
      k_rbf<<<dim3((int)((EH + 255)/256)), dim3(256), 0, stream>>>(rbf, Wrbf1, Wrbf2, RBF2, E);
      // t = silu(x@W_kj+b)*rbf2 -> TMP
      k_gemmb<0,128,128><<<dim3(mt,1), dim3(256), 0, stream>>>(XB,0, WTb+OFF_KJ,0, bkj,0, RBF2,0, TMP,0, 0, E);
      // x_kj = silu(t@W_down) -> XKJ
      k_gemmb<1,64,128><<<dim3(mt,1), dim3(256), 0, stream>>>(TMP,0, WTb+OFF_DOWN,0, (const float*)0,0, (const u16*)0,0, XKJ,0, 0, E);
      k_s1<<<dim3((T + 255)/256), dim3(256), 0, stream>>>(sbf, Wsbf1, S1, T);
      hipMemsetAsync(BUF, 0, 6*EI*4, stream);
      k_triplet<<<dim3((int)(((size_t)T*64 + 255)/256)), dim3(256), 0, stream>>>(ikj, iji, bt, S1, Wsbf2, XKJ, AGG, T, E);
      k_cvt<<<dim3((int)((EI + 255)/256)), dim3(256), 0, stream>>>(AGG, AGGB, (int)EI);

      // fully-fused chain: one dispatch covers all 7 slices x 7 GEMMs
      const int mt2 = (E + 255)/256;
      k_chain<<<dim3(mt2, 7), dim3(512), 0, stream>>>(XB, AGGB, WTb,
          bji, bbs1, bbs2, blin, bas1, bas2, OUT, E);
      // fold all 7 slices into d_out (slice 6 = generic -> alpha)
      k_red<<<dim3((int)((EH/4 + 255)/256)), dim3(256), 0, stream>>>(OUT, alphaP, (float*)d_out, EH, 7, 1, 0);
      (void)n_in; (void)out_size;
      return;
    }
  }

  // ---------- legacy fallback (verified path) ----------
  {
    char* ws = (char*)d_ws;
    size_t off = 0;
    auto arena = [&](size_t bytes)->size_t{
      size_t o = off; off += (bytes + 255) & ~(size_t)255; return o;
    };
    size_t oWT   = arena((size_t)WT_TOTAL*2);
    size_t oXB   = arena(EH*2);
    size_t oR0   = arena(EH*2);
    size_t oR1   = arena(EH*2);
    size_t oXKJ  = arena(EI*2);
    size_t oAGG  = arena(6*EI*4);
    size_t oAGGB = arena(7*EI*2);
    if (off > ws_size) return;

    u16*   WTb  = (u16*)(ws + oWT);
    u16*   XB   = (u16*)(ws + oXB);
    u16*   R0   = (u16*)(ws + oR0);
    u16*   R1   = (u16*)(ws + oR1);
    u16*   XKJ  = (u16*)(ws + oXKJ);
    float* AGG  = (float*)(ws + oAGG);
    u16*   AGGB = (u16*)(ws + oAGGB);
    float* ACC  = (float*)(ws + oAGG);
    float* S1   = (float*)(ws + oR0);

    tw.dst = WTb;
    hipLaunchKernelGGL(k_transpose, dim3(64, 44, 1), dim3(256, 1, 1), 0, stream, tw);
    k_f2b<<<dim3((int)((EH + 255)/256)), dim3(256), 0, stream>>>(x, XB, (int)EH);
    k_rbf<<<dim3((int)((EH + 255)/256)), dim3(256), 0, stream>>>(rbf, Wrbf1, Wrbf2, R0, E);
    k_gemm<EPI_MUL,128,128><<<dim3(mt), dim3(256), 0, stream>>>(XB, WTb + OFF_KJ, bkj, R0, nullptr, R1, nullptr, nullptr, E);
    k_gemm<EPI_ADD,64,128><<<dim3(mt), dim3(256), 0, stream>>>(R1, WTb + OFF_DOWN, nullptr, nullptr, nullptr, XKJ, nullptr, nullptr, E);
    k_s1<<<dim3((T + 255)/256), dim3(256), 0, stream>>>(sbf, Wsbf1, S1, T);
    hipMemsetAsync(ws + oAGG, 0, 6*EI*4, stream);
    k_triplet<<<dim3((int)(((size_t)T*64 + 255)/256)), dim3(256), 0, stream>>>(ikj, iji, bt, S1, Wsbf2, XKJ, AGG, T, E);
    k_cvt<<<dim3((int)((EI + 255)/256)), dim3(256), 0, stream>>>(AGG, AGGB, (int)EI);
    hipMemsetAsync(ws + oAGG, 0, EH*4, stream);

    for (int c = 0; c < 7; c++){
      const int b    = (c < 6) ? c : 5;
      const int slot = (c < 6) ? c : 6;
      const u16* aggA = AGGB + (size_t)slot*EI;
      k_gemm<EPI_ADD,128,64><<<dim3(mt), dim3(256), 0, stream>>>(aggA, WTb + OFF_UP + b*8192, nullptr, nullptr, nullptr, R0, nullptr, nullptr, E);
      k_gemm<EPI_ADD,128,128><<<dim3(mt), dim3(256), 0, stream>>>(XB, WTb + OFF_JI + b*16384, bji + b*128, R0, nullptr, R1, nullptr, nullptr, E);
      k_gemm<EPI_ADD,128,128><<<dim3(mt), dim3(256), 0, stream>>>(R1, WTb + OFF_BS1 + b*16384, bbs1 + b*128, nullptr, nullptr, R0, nullptr, nullptr, E);
      k_gemm<EPI_ADD,128,128><<<dim3(mt), dim3(256), 0, stream>>>(R0, WTb + OFF_BS2 + b*16384, bbs2 + b*128, R1, nullptr, R1, nullptr, nullptr, E);
      k_gemm<EPI_ADD,128,128><<<dim3(mt), dim3(256), 0, stream>>>(R1, WTb + OFF_LIN + b*16384, blin + b*128, XB, nullptr, R0, nullptr, nullptr, E);
      k_gemm<EPI_ADD,128,128><<<dim3(mt), dim3(256), 0, stream>>>(R0, WTb + OFF_AS1 + b*16384, bas1 + b*128, nullptr, nullptr, R1, nullptr, nullptr, E);
      if (c < 6)
        k_gemm<EPI_ACC,128,128><<<dim3(mt), dim3(256), 0, stream>>>(R1, WTb + OFF_AS2 + b*16384, bas2 + b*128, R0, ACC, nullptr, nullptr, alphaP, E);
      else
        k_gemm<EPI_FIN,128,128><<<dim3(mt), dim3(256), 0, stream>>>(R1, WTb + OFF_AS2 + b*16384, bas2 + b*128, R0, ACC, nullptr, (float*)d_out, alphaP, E);
    }
  }
  (void)n_in; (void)out_size;
}